// Round 1
// baseline (238.060 us; speedup 1.0000x reference)
//
#include <hip/hip_runtime.h>
#include <hip/hip_bf16.h>

#define KK 128
#define VV 50000
#define DD 8192
#define NN 512

// EPS = 0.01 * 100^(-0.55) computed in double, matching Python float
#define EPS_F      0.0007943282347242814f
#define EPS_HALF_F 0.0003971641173621407f
#define ZERO_F     1e-6f

// output layout (flat float32, in return order)
#define OFF_ETA 0
#define OFF_Z2  ((size_t)DD * KK)                    // 1048576
#define OFF_CDK (OFF_Z2 + (size_t)DD * NN)           // 5242880
#define OFF_CWK (OFF_CDK + (size_t)DD * KK)          // 6291456
#define OFF_CK  (OFF_CWK + (size_t)VV * KK)          // 12691456

__device__ __forceinline__ float jexpf(float x) {
    x = fminf(fmaxf(x, -700.0f), 700.0f);
    return fmaxf(expf(x), ZERO_F);
}

__global__ __launch_bounds__(256) void dtm_main(
    const int* __restrict__ word_ids, const int* __restrict__ z,
    const float* __restrict__ eta, const float* __restrict__ alpha,
    const float* __restrict__ phi, const int* __restrict__ prop_word,
    const int* __restrict__ prop_topic, const float* __restrict__ u_word,
    const float* __restrict__ u_topic, const float* __restrict__ xi,
    float* __restrict__ out)
{
    const int d = blockIdx.x;
    const int tid = threadIdx.x;

    __shared__ int   cnt0[KK];
    __shared__ int   cnt2[KK];
    __shared__ float etan[KK];
    __shared__ float sred[KK];

    if (tid < KK) { cnt0[tid] = 0; cnt2[tid] = 0; }
    __syncthreads();

    const int tb = d * NN;

    // vectorized token loads: thread handles tokens 2*tid and 2*tid+1
    const int2*   zp   = (const int2*)(z + tb);
    const int2*   wp   = (const int2*)(word_ids + tb);
    const int2*   p1p  = (const int2*)(prop_word + tb);
    const int2*   p2p  = (const int2*)(prop_topic + tb);
    const float2* uwp  = (const float2*)(u_word + tb);
    const float2* utp  = (const float2*)(u_topic + tb);

    int2   zz = zp[tid];
    int2   ww = wp[tid];
    int2   pp1 = p1p[tid];
    int2   pp2 = p2p[tid];
    float2 uw = uwp[tid];
    float2 ut = utp[tid];

    atomicAdd(&cnt0[zz.x], 1);
    atomicAdd(&cnt0[zz.y], 1);
    __syncthreads();

    // ---- softmax over eta[d,:] + SGLD eta update (threads 0..127) ----
    float e = 0.0f, ex = 0.0f;
    if (tid < KK) { e = eta[(size_t)d * KK + tid]; sred[tid] = e; }
    __syncthreads();
    for (int s = 64; s > 0; s >>= 1) {
        if (tid < s) sred[tid] = fmaxf(sred[tid], sred[tid + s]);
        __syncthreads();
    }
    float mx = sred[0];
    __syncthreads();
    if (tid < KK) { ex = expf(e - mx); sred[tid] = ex; }
    __syncthreads();
    for (int s = 64; s > 0; s >>= 1) {
        if (tid < s) sred[tid] += sred[tid + s];
        __syncthreads();
    }
    float ssum = sred[0];
    if (tid < KK) {
        float sm = ex / ssum;
        float grad  = (float)cnt0[tid] - (float)NN * sm;
        float prior = alpha[tid] - e;           // ETA_VAR = 1
        float en = e + EPS_HALF_F * (grad + prior) + xi[d] * EPS_F;
        etan[tid] = en;
        out[OFF_ETA + (size_t)d * KK + tid] = en;
    }
    __syncthreads();

    // ---- MH steps per token ----
    float* z2out = out + OFF_Z2 + tb;
    float* cwk2  = out + OFF_CWK;

    {
        float a1 = jexpf(phi[(size_t)ww.x * KK + pp1.x]) / jexpf(phi[(size_t)ww.x * KK + zz.x]);
        int z1 = (uw.x < a1) ? pp1.x : zz.x;
        float a2 = jexpf(etan[pp2.x]) / jexpf(etan[z1]);
        int z2v = (ut.x < a2) ? pp2.x : z1;
        z2out[2 * tid] = (float)z2v;
        atomicAdd(&cnt2[z2v], 1);
        atomicAdd(&cwk2[(size_t)ww.x * KK + z2v], 1.0f);
    }
    {
        float a1 = jexpf(phi[(size_t)ww.y * KK + pp1.y]) / jexpf(phi[(size_t)ww.y * KK + zz.y]);
        int z1 = (uw.y < a1) ? pp1.y : zz.y;
        float a2 = jexpf(etan[pp2.y]) / jexpf(etan[z1]);
        int z2v = (ut.y < a2) ? pp2.y : z1;
        z2out[2 * tid + 1] = (float)z2v;
        atomicAdd(&cnt2[z2v], 1);
        atomicAdd(&cwk2[(size_t)ww.y * KK + z2v], 1.0f);
    }
    __syncthreads();

    if (tid < KK) {
        out[OFF_CDK + (size_t)d * KK + tid] = (float)cnt2[tid];
    }
}

// CK2[k] = sum_d CDK2[d,k]; 128 blocks x 256 threads, each block sums 64 docs
__global__ __launch_bounds__(256) void ck_reduce(const float* __restrict__ cdk2,
                                                 float* __restrict__ ck2)
{
    const int b = blockIdx.x;
    const int tid = threadIdx.x;
    const size_t base = (size_t)b * 64 * KK;   // 64 docs per block
    float part = 0.0f;
    for (int i = tid; i < 64 * KK; i += 256)   // i % 128 == tid % 128
        part += cdk2[base + i];
    __shared__ float s[256];
    s[tid] = part;
    __syncthreads();
    if (tid < KK)
        atomicAdd(&ck2[tid], s[tid] + s[tid + KK]);
}

extern "C" void kernel_launch(void* const* d_in, const int* in_sizes, int n_in,
                              void* d_out, int out_size, void* d_ws, size_t ws_size,
                              hipStream_t stream) {
    const int*   word_ids   = (const int*)d_in[0];
    const int*   z          = (const int*)d_in[1];
    const float* eta        = (const float*)d_in[2];
    const float* alpha      = (const float*)d_in[3];
    const float* phi        = (const float*)d_in[4];
    const int*   prop_word  = (const int*)d_in[5];
    const int*   prop_topic = (const int*)d_in[6];
    const float* u_word     = (const float*)d_in[7];
    const float* u_topic    = (const float*)d_in[8];
    const float* xi         = (const float*)d_in[9];
    float* out = (float*)d_out;

    // zero CWK2 + CK2 (atomically accumulated into)
    hipMemsetAsync(out + OFF_CWK, 0, ((size_t)VV * KK + KK) * sizeof(float), stream);

    dtm_main<<<DD, 256, 0, stream>>>(word_ids, z, eta, alpha, phi,
                                     prop_word, prop_topic, u_word, u_topic, xi, out);

    ck_reduce<<<KK, 256, 0, stream>>>(out + OFF_CDK, out + OFF_CK);
}